// Round 5
// baseline (377.063 us; speedup 1.0000x reference)
//
#include <hip/hip_runtime.h>
#include <hip/hip_bf16.h>
#include <cstdint>
#include <cstddef>

#define SCALE 0.42044820762685725f  // 32^(-1/4)

typedef __attribute__((ext_vector_type(8))) short short8;
typedef __attribute__((ext_vector_type(4))) short short4v;
typedef __attribute__((ext_vector_type(4))) float f32x4;

__device__ __forceinline__ unsigned int pk2bf(float lo, float hi) {
    __hip_bfloat162 h = __float22bfloat162_rn(float2{lo, hi});  // v_cvt_pk_bf16_f32
    unsigned int u;
    __builtin_memcpy(&u, &h, sizeof(u));
    return u;
}
__device__ __forceinline__ unsigned short f2bf(float f) {
    unsigned int u = __builtin_bit_cast(unsigned int, f);
    u = (u + 0x7fffu + ((u >> 16) & 1u)) >> 16;   // RNE
    return (unsigned short)u;
}
__device__ __forceinline__ float bf2f(unsigned short h) {
    unsigned int u = ((unsigned int)h) << 16;
    return __builtin_bit_cast(float, u);
}

// ---------------- prepack ----------------
// [0, 393216) bytes: W A-frags bf16. mtg 0..31: KV rows 256+mtg*16; mtg 32..47: Q rows (mtg-32)*16.
//   idx = ((mtg*8+ks)*64+lane)*8+j <-> W[row(mtg)+(lane&15)][ks*32+(lane>>4)*8+j]
// [393216, 425984): posT bf16 [k=64][m=256]: posT[k*256+m] = bf16(pos[m*64+k])
__global__ __launch_bounds__(256) void prepack_w(const float* __restrict__ w,
                                                 const float* __restrict__ pos,
                                                 unsigned short* __restrict__ wp,
                                                 unsigned short* __restrict__ pT) {
    int gid = blockIdx.x * 256 + threadIdx.x;    // < 40960
    if (gid < 24576) {
        int lane = gid & 63;
        int ks   = (gid >> 6) & 7;
        int mtg  = gid >> 9;                     // 0..47
        int row  = (mtg < 32 ? 256 + mtg * 16 : (mtg - 32) * 16) + (lane & 15);
        int k0   = ks * 32 + (lane >> 4) * 8;
        const float* src = w + row * 256 + k0;
        short8 v;
#pragma unroll
        for (int j = 0; j < 8; ++j) v[j] = (short)f2bf(src[j]);
        *reinterpret_cast<short8*>(wp + (size_t)gid * 8) = v;
    } else {
        int u = gid - 24576;                     // k*256 + m, < 16384
        pT[u] = f2bf(pos[(u & 255) * 64 + (u >> 8)]);
    }
}

// ---------------- main fused kernel: one WG per 4 wq-consecutive tiles ----------------
// Wave w owns kv rows [64w,64w+64) and heads {2w,2w+1}. Attention is fully in-register.
// Double-buffered x LDS; next tile's x prefetched into regs during attention. 1 barrier/tile.
template <bool PRE>
__global__ __launch_bounds__(256, 2) void attn_fused(
        const float* __restrict__ x, const float* __restrict__ proj_w,
        const float* __restrict__ proj_b, const float* __restrict__ pos,
        const unsigned short* __restrict__ wpack, const unsigned short* __restrict__ posT,
        float* __restrict__ out) {
    __shared__ __align__(16) unsigned char s_x[2][32768];  // bf16 [p=64][c=256], XOR swizzled
    __shared__ float s_qbias[256];
    __shared__ float s_vbias[256];

    const int t    = threadIdx.x;
    const int lane = t & 63;
    const int wave = t >> 6;
    const int l15  = lane & 15;
    const int l4   = lane >> 4;

    s_qbias[t] = proj_b[t];         // wave-local ranges: no barrier needed
    s_vbias[t] = proj_b[512 + t];

    const int tile0 = blockIdx.x * 4;   // 4 consecutive wq: shares 128B x-lines within WG

    float2 xv[32];                      // prefetch buffer: live only during attention phase

    auto issue_x = [&](int tile) {
        int b = tile >> 8, hq = (tile >> 4) & 15, wq = tile & 15;
        const float* xb  = x + (size_t)b * 4194304 + (size_t)(hq * 8) * 128 + wq * 8;
        const int px0 = lane & ~1;
        const int pl  = lane & 1;
        const float* xpx = xb + (px0 >> 3) * 128 + (px0 & 7);
#pragma unroll
        for (int h = 0; h < 8; ++h)
#pragma unroll
            for (int j = 0; j < 4; ++j) {
                int c = h * 32 + wave * 8 + 2 * j + pl;
                xv[h * 4 + j] = *reinterpret_cast<const float2*>(xpx + (size_t)c * 16384);
            }
    };
    auto write_x = [&](int buf) {
        const int p = lane, pl = lane & 1;
        unsigned char* base = s_x[buf];
#pragma unroll
        for (int h = 0; h < 8; ++h) {
            uint4 pk;
            unsigned int* pku = &pk.x;
#pragma unroll
            for (int j = 0; j < 4; ++j) {
                float2 v = xv[h * 4 + j];
                float sel   = pl ? v.x : v.y;
                float other = __shfl_xor(sel, 1);
                pku[j] = pl ? pk2bf(other, v.y) : pk2bf(v.x, other);
            }
            int c8 = h * 4 + wave;
            *reinterpret_cast<uint4*>(base + p * 512 + ((c8 * 16) ^ ((p & 7) << 4))) = pk;
        }
    };

    issue_x(tile0);
    write_x(0);
    __syncthreads();

#pragma unroll 1
    for (int ti = 0; ti < 4; ++ti) {
        const int tile = tile0 + ti;
        const int b = tile >> 8, hq = (tile >> 4) & 15, wq = tile & 15;
        const int buf = ti & 1;
        const unsigned char* xl = s_x[buf];

        f32x4 acc[4][4], accQ[4];
        unsigned int kpk[4][4][2];

        // ---- pass 1: keys (rows 256..511) + q (rows 0..255, B-cols 0..15) ----
#pragma unroll
        for (int mt = 0; mt < 4; ++mt) {
            accQ[mt] = (f32x4){0.f, 0.f, 0.f, 0.f};
#pragma unroll
            for (int nt = 0; nt < 4; ++nt) acc[mt][nt] = (f32x4){0.f, 0.f, 0.f, 0.f};
        }
#pragma unroll 2
        for (int ks = 0; ks < 8; ++ks) {
            short8 bfr[4];
#pragma unroll
            for (int nt = 0; nt < 4; ++nt) {
                int n  = nt * 16 + l15;
                int kb = ks * 32 + l4 * 8;
                bfr[nt] = *reinterpret_cast<const short8*>(xl + n * 512 + ((2 * kb) ^ ((n & 7) << 4)));
            }
            short8 afk[4], afq[4];
#pragma unroll
            for (int mt = 0; mt < 4; ++mt) {
                if (PRE) {
                    afk[mt] = *reinterpret_cast<const short8*>(
                        wpack + ((size_t)(((wave * 4 + mt) * 8 + ks) * 64 + lane)) * 8);
                    afq[mt] = *reinterpret_cast<const short8*>(
                        wpack + ((size_t)(((32 + wave * 4 + mt) * 8 + ks) * 64 + lane)) * 8);
                } else {
                    const float* wk = proj_w + (256 + (wave * 4 + mt) * 16 + l15) * 256 + ks * 32 + l4 * 8;
                    const float* wq2 = proj_w + ((wave * 4 + mt) * 16 + l15) * 256 + ks * 32 + l4 * 8;
#pragma unroll
                    for (int j = 0; j < 8; ++j) { afk[mt][j] = (short)f2bf(wk[j]); afq[mt][j] = (short)f2bf(wq2[j]); }
                }
            }
#pragma unroll
            for (int mt = 0; mt < 4; ++mt)
#pragma unroll
                for (int nt = 0; nt < 4; ++nt)
                    acc[mt][nt] = __builtin_amdgcn_mfma_f32_16x16x32_bf16(afk[mt], bfr[nt], acc[mt][nt], 0, 0, 0);
#pragma unroll
            for (int mt = 0; mt < 4; ++mt)
                accQ[mt] = __builtin_amdgcn_mfma_f32_16x16x32_bf16(afq[mt], bfr[0], accQ[mt], 0, 0, 0);
        }

        // pack keys to bf16 regs (no key bias: softmax shift-invariant)
#pragma unroll
        for (int mt = 0; mt < 4; ++mt)
#pragma unroll
            for (int nt = 0; nt < 4; ++nt) {
                kpk[mt][nt][0] = pk2bf(acc[mt][nt][0], acc[mt][nt][1]);
                kpk[mt][nt][1] = pk2bf(acc[mt][nt][2], acc[mt][nt][3]);
            }

        // ---- pass 2: values (rows 512..767), reuse acc ----
#pragma unroll
        for (int mt = 0; mt < 4; ++mt)
#pragma unroll
            for (int nt = 0; nt < 4; ++nt) acc[mt][nt] = (f32x4){0.f, 0.f, 0.f, 0.f};
#pragma unroll 2
        for (int ks = 0; ks < 8; ++ks) {
            short8 bfr[4];
#pragma unroll
            for (int nt = 0; nt < 4; ++nt) {
                int n  = nt * 16 + l15;
                int kb = ks * 32 + l4 * 8;
                bfr[nt] = *reinterpret_cast<const short8*>(xl + n * 512 + ((2 * kb) ^ ((n & 7) << 4)));
            }
            short8 afv[4];
#pragma unroll
            for (int mt = 0; mt < 4; ++mt) {
                if (PRE) {
                    afv[mt] = *reinterpret_cast<const short8*>(
                        wpack + ((size_t)(((16 + wave * 4 + mt) * 8 + ks) * 64 + lane)) * 8);
                } else {
                    const float* wv = proj_w + (512 + (wave * 4 + mt) * 16 + l15) * 256 + ks * 32 + l4 * 8;
#pragma unroll
                    for (int j = 0; j < 8; ++j) afv[mt][j] = (short)f2bf(wv[j]);
                }
            }
#pragma unroll
            for (int mt = 0; mt < 4; ++mt)
#pragma unroll
                for (int nt = 0; nt < 4; ++nt)
                    acc[mt][nt] = __builtin_amdgcn_mfma_f32_16x16x32_bf16(afv[mt], bfr[nt], acc[mt][nt], 0, 0, 0);
        }

        // ---- pos prefetch (L2, bf16) — issued BEFORE x so attention never drains x ----
        short4v pos4[4][4];
        if (PRE) {
#pragma unroll
            for (int nt = 0; nt < 4; ++nt)
#pragma unroll
                for (int mt = 0; mt < 4; ++mt)
                    pos4[nt][mt] = *reinterpret_cast<const short4v*>(
                        posT + (size_t)(nt * 16 + l15) * 256 + wave * 64 + mt * 16 + l4 * 4);
        }

        // ---- prefetch next tile's x (HBM) — hidden under attention ----
        if (ti < 3) issue_x(tile0 + ti + 1);

        // ---- attention: fully in-register ----
        float qv[4][4];
#pragma unroll
        for (int mt = 0; mt < 4; ++mt)
#pragma unroll
            for (int i = 0; i < 4; ++i)
                qv[mt][i] = SCALE * (__shfl(accQ[mt][i], lane & 48)
                                     + s_qbias[wave * 64 + mt * 16 + l4 * 4 + i]);

        float lg[2][4], attnw[2][4];
#pragma unroll
        for (int hs = 0; hs < 2; ++hs)
#pragma unroll
            for (int nt = 0; nt < 4; ++nt) {
                float p = 0.f;
#pragma unroll
                for (int mh = 0; mh < 2; ++mh) {
                    int mt = hs * 2 + mh;
                    float kf[4];
                    kf[0] = bf2f((unsigned short)(kpk[mt][nt][0] & 0xffffu));
                    kf[1] = bf2f((unsigned short)(kpk[mt][nt][0] >> 16));
                    kf[2] = bf2f((unsigned short)(kpk[mt][nt][1] & 0xffffu));
                    kf[3] = bf2f((unsigned short)(kpk[mt][nt][1] >> 16));
#pragma unroll
                    for (int i = 0; i < 4; ++i) {
                        float pf = PRE ? bf2f((unsigned short)pos4[nt][mt][i])
                                       : pos[(size_t)(wave * 64 + mt * 16 + l4 * 4 + i) * 64 + nt * 16 + l15];
                        p = fmaf(qv[mt][i], fmaf(SCALE, kf[i], pf), p);
                    }
                }
                p += __shfl_xor(p, 16);   // reduce over l4 (d-groups)
                p += __shfl_xor(p, 32);
                lg[hs][nt] = p;
            }
#pragma unroll
        for (int hs = 0; hs < 2; ++hs) {
            float mx = fmaxf(fmaxf(lg[hs][0], lg[hs][1]), fmaxf(lg[hs][2], lg[hs][3]));
            mx = fmaxf(mx, __shfl_xor(mx, 1));
            mx = fmaxf(mx, __shfl_xor(mx, 2));
            mx = fmaxf(mx, __shfl_xor(mx, 4));
            mx = fmaxf(mx, __shfl_xor(mx, 8));
            float e0 = __expf(lg[hs][0] - mx), e1 = __expf(lg[hs][1] - mx);
            float e2 = __expf(lg[hs][2] - mx), e3 = __expf(lg[hs][3] - mx);
            float s = (e0 + e1) + (e2 + e3);
            s += __shfl_xor(s, 1);
            s += __shfl_xor(s, 2);
            s += __shfl_xor(s, 4);
            s += __shfl_xor(s, 8);
            float rs = 1.f / s;
            attnw[hs][0] = e0 * rs; attnw[hs][1] = e1 * rs;
            attnw[hs][2] = e2 * rs; attnw[hs][3] = e3 * rs;
        }

        // ---- epilogue: out = attn @ values from own acc; Σattn=1 folds value bias ----
#pragma unroll
        for (int mt = 0; mt < 4; ++mt) {
            int hs = mt >> 1;
#pragma unroll
            for (int i = 0; i < 4; ++i) {
                float sum = attnw[hs][0] * acc[mt][0][i] + attnw[hs][1] * acc[mt][1][i]
                          + attnw[hs][2] * acc[mt][2][i] + attnw[hs][3] * acc[mt][3][i];
                sum += __shfl_xor(sum, 1);
                sum += __shfl_xor(sum, 2);
                sum += __shfl_xor(sum, 4);
                sum += __shfl_xor(sum, 8);
                if (l15 == 0) {
                    int vr = wave * 64 + mt * 16 + l4 * 4 + i;
                    out[(size_t)b * 65536 + (size_t)vr * 256 + hq * 16 + wq] = sum + s_vbias[vr];
                }
            }
        }

        // ---- publish next tile's x; single barrier per tile ----
        if (ti < 3) write_x(buf ^ 1);
        __syncthreads();
    }
}

extern "C" void kernel_launch(void* const* d_in, const int* in_sizes, int n_in,
                              void* d_out, int out_size, void* d_ws, size_t ws_size,
                              hipStream_t stream) {
    (void)in_sizes; (void)n_in; (void)out_size;
    const float* x      = (const float*)d_in[0];
    const float* proj_w = (const float*)d_in[1];
    const float* proj_b = (const float*)d_in[2];
    const float* pos    = (const float*)d_in[3];
    float* out = (float*)d_out;

    const size_t need_ws = 393216 + 32768;   // A-frags bf16 + posT bf16
    if (d_ws != nullptr && ws_size >= need_ws) {
        unsigned short* wp = (unsigned short*)d_ws;
        unsigned short* pT = (unsigned short*)((char*)d_ws + 393216);
        prepack_w<<<160, 256, 0, stream>>>(proj_w, pos, wp, pT);
        attn_fused<true><<<512, 256, 0, stream>>>(x, proj_w, proj_b, pos, wp, pT, out);
    } else {
        attn_fused<false><<<512, 256, 0, stream>>>(x, proj_w, proj_b, pos, nullptr, nullptr, out);
    }
}